// Round 12
// baseline (258.246 us; speedup 1.0000x reference)
//
#include <hip/hip_runtime.h>

typedef unsigned short u16;
typedef unsigned int u32;
typedef __bf16 bf16x8 __attribute__((ext_vector_type(8)));
typedef float f32x4 __attribute__((ext_vector_type(4)));
typedef float f32x16 __attribute__((ext_vector_type(16)));
typedef u32 u32x4 __attribute__((ext_vector_type(4)));

#define MFMA_BF16(a, b, c) __builtin_amdgcn_mfma_f32_16x16x32_bf16((a), (b), (c), 0, 0, 0)
#define MFMA32(a, b, c) __builtin_amdgcn_mfma_f32_32x32x16_bf16((a), (b), (c), 0, 0, 0)

// log2-domain constant: 0.125 * log2(e), folded into w_qkv Q-rows at prep
#define QSCALE 0.18033688011112042f

#define BARRIER __builtin_amdgcn_s_barrier()
#define LGKM0                                                \
  do {                                                       \
    asm volatile("s_waitcnt lgkmcnt(0)" ::: "memory");       \
    __builtin_amdgcn_sched_barrier(0);                       \
  } while (0)
#define WAIT_VM(N) asm volatile("s_waitcnt vmcnt(" #N ")" ::: "memory")

// ---------- helpers ----------

__device__ __forceinline__ u16 f2bf(float f) {
  u32 u = __builtin_bit_cast(u32, f);
  u += 0x7fffu + ((u >> 16) & 1u);   // RNE
  return (u16)(u >> 16);
}

__device__ __forceinline__ void async_copy16(const void* g, void* l) {
  __builtin_amdgcn_global_load_lds(
      (__attribute__((address_space(1))) void*)g,
      (__attribute__((address_space(3))) void*)l, 16, 0, 0);
}

__device__ __forceinline__ u32 cvt_pk_bf16(float lo, float hi) {
  u32 d;
  asm("v_cvt_pk_bf16_f32 %0, %1, %2" : "=v"(d) : "v"(lo), "v"(hi));
  return d;
}

__device__ __forceinline__ void swap32(u32& a, u32& b) {
  asm("v_permlane32_swap_b32 %0, %1" : "+v"(a), "+v"(b));
}

// ---------- kernel 0: fused fp32->bf16 converts + RoPE cos/sin table ----------

__global__ __launch_bounds__(256) void prep_kernel(
    const float* __restrict__ x_f, const float* __restrict__ wqkv_f,
    const float* __restrict__ wo_f, u16* __restrict__ xb,
    u16* __restrict__ wqkvb, u16* __restrict__ wob, float2* __restrict__ rope_t) {
  const int blk = blockIdx.x;
  if (blk < 12288) {
    const float* src;
    u16* dst;
    int base;
    float scale = 1.0f;
    if (blk < 8192)      { src = x_f;    dst = xb;    base = blk; }
    else if (blk < 11264){ src = wqkv_f; dst = wqkvb; base = blk - 8192;
                           if (base < 1024) scale = QSCALE; }  // Q rows
    else                 { src = wo_f;   dst = wob;   base = blk - 11264; }
    const int i = base * 1024 + threadIdx.x * 4;
    const float4 v = *(const float4*)(src + i);
    ushort4 o;
    o.x = f2bf(v.x * scale); o.y = f2bf(v.y * scale);
    o.z = f2bf(v.z * scale); o.w = f2bf(v.w * scale);
    *(ushort4*)(dst + i) = o;
  } else {
    const int idx = (blk - 12288) * 256 + threadIdx.x;  // [0, 65536)
    const int s = idx >> 5, i = idx & 31;
    const float invf = __builtin_amdgcn_exp2f(-(float)i * 0.41524101186092027f);
    float rev = (float)s * invf * 0.15915494309189535f;  // radians -> revolutions
    rev -= floorf(rev);
    rope_t[idx] = make_float2(__builtin_amdgcn_cosf(rev), __builtin_amdgcn_sinf(rev));
  }
}

// ---------- 256x128 GEMM-BT core, BK=32 TRIPLE-buffer, 1 barrier/K-step ------
// (r8 structure, verified: qkv 80.6 -> <68 µs). 512 thr = 8 waves (4M x 2N);
// per-wave 64x64 = acc[4][4]; 72 KB LDS -> 2 blocks/CU (16 waves).
// stage(t+2) targets buf (t+2)%3, disjoint from read buf -> 1 barrier/K-step;
// counted WAIT_VM(3). BK=32 rows are 64B -> naturally conflict-free reads.

__device__ __forceinline__ void gemm_tb(const u16* __restrict__ A,
                                        const u16* __restrict__ B,
                                        int row0, int col0, u16* lds,
                                        f32x4 acc[4][4]) {
  const int tid = threadIdx.x;
  const int wave = tid >> 6, lane = tid & 63;
  const int fr = lane & 15, quad = lane >> 4;
  const int wm = (wave >> 1) * 64;   // 0,64,128,192
  const int wn = (wave & 1) * 64;    // 0,64

  f32x4 zero = {0.f, 0.f, 0.f, 0.f};
#pragma unroll
  for (int mt = 0; mt < 4; ++mt)
#pragma unroll
    for (int nt = 0; nt < 4; ++nt) acc[mt][nt] = zero;

  // stage K-step t into buf t%3: A 2 insts + B 1 inst per thread
  auto stage = [&](int t) {
    u16* base = lds + (t % 3) * 12288;
    const int k0 = t * 32;
#pragma unroll
    for (int it = 0; it < 2; ++it) {
      const int slot = it * 512 + tid;   // 0..1023
      const int row = slot >> 2, g = slot & 3;
      async_copy16(A + (size_t)(row0 + row) * 1024 + k0 + g * 8, base + slot * 8);
    }
    const int row = tid >> 2, g = tid & 3;
    async_copy16(B + (size_t)(col0 + row) * 1024 + k0 + g * 8,
                 base + 8192 + tid * 8);
  };

  const int aoff = fr * 32 + quad * 8;   // within-A row/frag offset
  stage(0);
  stage(1);
  WAIT_VM(3);   // step 0's 3 loads landed
  BARRIER;

  for (int t = 0; t < 32; ++t) {
    const u16* bs = lds + (t % 3) * 12288;

    bf16x8 a[4], b[4];
#pragma unroll
    for (int m = 0; m < 4; ++m)
      a[m] = *(const bf16x8*)(bs + (wm + m * 16) * 32 + aoff);
#pragma unroll
    for (int n = 0; n < 4; ++n)
      b[n] = *(const bf16x8*)(bs + 8192 + (wn + n * 16) * 32 + aoff);

    if (t + 2 < 32) stage(t + 2);   // disjoint buf: no WAR with current reads

    LGKM0;
    __builtin_amdgcn_s_setprio(1);
#pragma unroll
    for (int m = 0; m < 4; ++m)
#pragma unroll
      for (int n = 0; n < 4; ++n)
        acc[m][n] = MFMA_BF16(a[m], b[n], acc[m][n]);
    __builtin_amdgcn_s_setprio(0);

    if (t + 2 < 32) { WAIT_VM(3); } else { WAIT_VM(0); }  // t+1 resident
    BARRIER;
  }
}

// ---------- 128x128 GEMM-BT core, same schedule, 256 thr (for oproj) ---------
// 4 waves (2M x 2N); per-wave 64x64 = acc[4][4] (identical per-wave work).
// LDS 3 x (A 8KB + B 8KB) = 48 KB -> 3 blocks/CU (12 waves).

__device__ __forceinline__ void gemm_tb128(const u16* __restrict__ A,
                                           const u16* __restrict__ B,
                                           int row0, int col0, u16* lds,
                                           f32x4 acc[4][4]) {
  const int tid = threadIdx.x;           // 0..255
  const int wave = tid >> 6, lane = tid & 63;
  const int fr = lane & 15, quad = lane >> 4;
  const int wm = (wave >> 1) * 64;       // 0,64
  const int wn = (wave & 1) * 64;        // 0,64

  f32x4 zero = {0.f, 0.f, 0.f, 0.f};
#pragma unroll
  for (int mt = 0; mt < 4; ++mt)
#pragma unroll
    for (int nt = 0; nt < 4; ++nt) acc[mt][nt] = zero;

  // stage K-step t into buf t%3: 2 A insts + 2 B insts per thread (4 total)
  auto stage = [&](int t) {
    u16* base = lds + (t % 3) * 8192;
    const int k0 = t * 32;
#pragma unroll
    for (int it = 0; it < 2; ++it) {
      const int slot = it * 256 + tid;   // 0..511
      const int row = slot >> 2, g = slot & 3;
      async_copy16(A + (size_t)(row0 + row) * 1024 + k0 + g * 8, base + slot * 8);
      async_copy16(B + (size_t)(col0 + row) * 1024 + k0 + g * 8,
                   base + 4096 + slot * 8);
    }
  };

  const int aoff = fr * 32 + quad * 8;
  stage(0);
  stage(1);
  WAIT_VM(4);   // step 0's 4 loads landed
  BARRIER;

  for (int t = 0; t < 32; ++t) {
    const u16* bs = lds + (t % 3) * 8192;

    bf16x8 a[4], b[4];
#pragma unroll
    for (int m = 0; m < 4; ++m)
      a[m] = *(const bf16x8*)(bs + (wm + m * 16) * 32 + aoff);
#pragma unroll
    for (int n = 0; n < 4; ++n)
      b[n] = *(const bf16x8*)(bs + 4096 + (wn + n * 16) * 32 + aoff);

    if (t + 2 < 32) stage(t + 2);

    LGKM0;
    __builtin_amdgcn_s_setprio(1);
#pragma unroll
    for (int m = 0; m < 4; ++m)
#pragma unroll
      for (int n = 0; n < 4; ++n)
        acc[m][n] = MFMA_BF16(a[m], b[n], acc[m][n]);
    __builtin_amdgcn_s_setprio(0);

    if (t + 2 < 32) { WAIT_VM(4); } else { WAIT_VM(0); }
    BARRIER;
  }
}

// ---------- kernel 1: QKV projection + RoPE (r8 structure, unchanged) --------
// 256x128 tiles: grid (24, 32) = 768 blocks at 2 blocks/CU; XCD-chunked remap.

__global__ __launch_bounds__(512, 4) void qkv_rope_kernel(
    const u16* __restrict__ x, const u16* __restrict__ w_qkv,
    const float2* __restrict__ rope_t,
    u16* __restrict__ q_ws, u16* __restrict__ k_ws, u16* __restrict__ vt_ws) {
  __shared__ u16 lds[36864];  // 72 KB: gemm triple-buf; epilogue reuses it
  f32x4 acc[4][4];
  const int lin0 = blockIdx.x + 24 * blockIdx.y;   // 0..767
  const int lin = (lin0 & 7) * 96 + (lin0 >> 3);   // bijective XCD-chunk remap
  const int row0 = (lin / 24) * 256;  // M = 8192
  const int col0 = (lin % 24) * 128;  // N = 3072
  gemm_tb(x, w_qkv, row0, col0, lds, acc);

  const int tid = threadIdx.x;
  const int wave = tid >> 6, lane = tid & 63;
  const int fr = lane & 15, quad = lane >> 4;
  const int wm = (wave >> 1) * 64, wn = (wave & 1) * 64;
  const int region = col0 >> 10;      // 0=Q 1=K 2=V (block-uniform; 1024%128==0)
  const int f0 = col0 & 1023;
  const int s0r = row0 & 2047;
  const int bb = row0 >> 11;
  const int h0 = f0 >> 6;             // block covers heads h0, h0+1

  if (region < 2) {
    // rotate in registers, stage [m 256][n 128] (stride 136)
#pragma unroll
    for (int mt = 0; mt < 4; ++mt) {
#pragma unroll
      for (int nt = 0; nt < 4; ++nt) {
        const int n = wn + nt * 16 + fr;
        const int d = n & 63;  // col0/wn are 64-aligned
#pragma unroll
        for (int r = 0; r < 4; ++r) {
          const int m = wm + mt * 16 + quad * 4 + r;
          const float own = acc[mt][nt][r];
          const float part = __shfl_xor(own, 1);
          const int s = s0r + m;
          const float2 cssn = rope_t[s * 32 + (d >> 1)];
          const float val = (d & 1) ? (part * cssn.y + own * cssn.x)
                                    : (own * cssn.x - part * cssn.y);
          lds[m * 136 + n] = f2bf(val);
        }
      }
    }
    __syncthreads();
    u16* dst = (region == 0) ? q_ws : k_ws;
#pragma unroll
    for (int j = 0; j < 8; ++j) {
      const int idx2 = j * 512 + tid;       // 0..4095
      const int m = idx2 >> 4;              // 0..255
      const int rem = idx2 & 15;
      const int hf = rem >> 3;              // head half (0/1)
      const int c8 = (rem & 7) * 8;
      const uint4 v = *(const uint4*)(lds + m * 136 + hf * 64 + c8);
      *(uint4*)(dst + ((size_t)(bb * 16 + h0 + hf) * 2048 + s0r + m) * 64 + c8) = v;
    }
  } else {
    // stage transposed [n 128][m 256] (stride 264)
#pragma unroll
    for (int mt = 0; mt < 4; ++mt)
#pragma unroll
      for (int nt = 0; nt < 4; ++nt) {
        const int n = wn + nt * 16 + fr;
#pragma unroll
        for (int r = 0; r < 4; ++r) {
          const int m = wm + mt * 16 + quad * 4 + r;
          lds[n * 264 + m] = f2bf(acc[mt][nt][r]);
        }
      }
    __syncthreads();
#pragma unroll
    for (int j = 0; j < 8; ++j) {
      const int idx2 = j * 512 + tid;       // 0..4095
      const int n = idx2 >> 5;              // 0..127
      const int mc = (idx2 & 31) * 8;       // 0..248
      const int h = h0 + (n >> 6);
      const int d = n & 63;
      const uint4 v = *(const uint4*)(lds + n * 264 + mc);
      *(uint4*)(vt_ws + ((size_t)(bb * 16 + h) * 64 + d) * 2048 + s0r + mc) = v;
    }
  }
}

// ---------- kernel 2: causal flash attention, swapped-QK 32x32 in-reg softmax -
// r3 structure; occupancy raised 3 -> 4 blocks/CU (LDS 33 KB x 4 = 133 <= 160,
// VGPR 72 allows 4 waves/SIMD). 1024 blocks all co-resident; the balanced
// q-tile permutation makes each CU's 4 resident columns sum to equal work.

__global__ __launch_bounds__(256, 4) void flash_attn_kernel(
    const u16* __restrict__ Q, const u16* __restrict__ K, const u16* __restrict__ Vt,
    const int* __restrict__ pad, u16* __restrict__ O) {
  const int S = 2048;
  const int idx = blockIdx.x;
  const int bh = idx & 63;
  const int b = bh >> 4, h = bh & 15;
  // balanced q-tile remap: perm = [[0,1,2,3],[7,6,5,4],[8,9,10,11],[15,14,13,12]]
  const int j = (idx >> 6) & 3;
  const int sr = idx >> 8;
  const int qt_rev = (sr >> 1) * 8 + ((sr & 1) ? (7 - j) : j);
  const int q0 = (15 - qt_rev) * 128;
  const u16* Qh = Q + (size_t)bh * S * 64;
  const u16* Kh = K + (size_t)bh * S * 64;
  const u16* Vth = Vt + (size_t)bh * 64 * S;
  const int tid = threadIdx.x, wave = tid >> 6, lane = tid & 63;
  const int l31 = lane & 31, hi = lane >> 5, l7 = lane & 7;

  __shared__ u16 lds_k[2][64 * 64];    // dbuf [kpos 64][d 64] swizzled  16 KB
  __shared__ u16 lds_vt[2][64 * 64];   // dbuf [d 64][kpos 64] swizzled  16 KB
  __shared__ float lds_biasf[2][64];   // {0, -inf} per kpos             512 B

  const int qb = q0 + wave * 32;  // wave's first q row

  // Q as B-operand: lane holds Q[qb + l31][d = c*16 + hi*8 + 0..7]
  bf16x8 qfrag[4];
#pragma unroll
  for (int c = 0; c < 4; ++c)
    qfrag[c] = *(const bf16x8*)(Qh + (size_t)(qb + l31) * 64 + c * 16 + hi * 8);

  bf16x8 ones;
#pragma unroll
  for (int jj = 0; jj < 8; ++jj) ones[jj] = (__bf16)1.0f;

  f32x16 o_acc0, o_acc1, lacc;
#pragma unroll
  for (int r = 0; r < 16; ++r) { o_acc0[r] = 0.f; o_acc1[r] = 0.f; lacc[r] = 0.f; }

  const float NEG = -__builtin_inff();
  int pv0 = 1, pv1 = 1;

  auto stage = [&](int k0, int bufi) {
#pragma unroll
    for (int it = 0; it < 2; ++it) {
      const int slot = it * 256 + tid;   // 0..511
      const int row = slot >> 3;         // 0..63
      const int g = slot & 7;
      const int gs = (g ^ (row & 7)) * 8;  // inverse-swizzled source granule
      async_copy16(Kh + (size_t)(k0 + row) * 64 + gs, &lds_k[bufi][slot * 8]);
      async_copy16(Vth + (size_t)row * 2048 + k0 + gs, &lds_vt[bufi][slot * 8]);
    }
    if (tid < 64) lds_biasf[bufi][tid] = pad[b * S + k0 + tid] ? 0.f : NEG;
    const int pvn = pad[b * S + k0 + lane];   // per-wave ballot source
    if (bufi) pv1 = pvn; else pv0 = pvn;
  };

  const int kend = q0 + 64;  // last k-tile origin (inclusive)
  stage(0, 0);
  __syncthreads();  // drains vmcnt(0): tile 0 resident
  int cur = 0;

  for (int k0 = 0; k0 <= kend; k0 += 64) {
    if (k0 < kend) stage(k0 + 64, cur ^ 1);  // prefetch next tile

    if (k0 <= qb + 31) {  // wave-uniform: skip fully-masked tiles
      const u16* lk = lds_k[cur];
      const u16* lvt = lds_vt[cur];
      const float* lb = lds_biasf[cur];
      const int pvc = cur ? pv1 : pv0;
      const bool fast = (__ballot(pvc != 0) == ~0ull);
      const bool needMask = (k0 + 63 > qb);
      const int thrh = qb + l31 - k0 - 4 * hi;  // mask iff rm+32*kt > thrh

      // ---- QK^T swapped: S[kpos][q], kpos reg-mapped, q = l31 ----
      f32x16 sacc0, sacc1;
#pragma unroll
      for (int r = 0; r < 16; ++r) { sacc0[r] = 0.f; sacc1[r] = 0.f; }
#pragma unroll
      for (int c = 0; c < 4; ++c) {
        const int gsw = ((2 * c + hi) ^ l7) * 8;
        bf16x8 kf0 = *(const bf16x8*)(lk + l31 * 64 + gsw);
        bf16x8 kf1 = *(const bf16x8*)(lk + (l31 + 32) * 64 + gsw);
        sacc0 = MFMA32(kf0, qfrag[c], sacc0);
        sacc1 = MFMA32(kf1, qfrag[c], sacc1);
      }

      // ---- softmax in-register + pack to PV A-frags ----
      bf16x8 pa[2][2];
#pragma unroll
      for (int kt = 0; kt < 2; ++kt) {
        float pe[16];
        if (fast) {
#pragma unroll
          for (int r = 0; r < 16; ++r) {
            float s = (kt == 0) ? sacc0[r] : sacc1[r];
            if (needMask) {
              const int rm = (r & 3) + 8 * (r >> 2) + 32 * kt;
              s = (rm > thrh) ? NEG : s;
            }
            pe[r] = __builtin_amdgcn_exp2f(s);
          }
        } else {
          f32x4 bv[4];
#pragma unroll
          for (int g = 0; g < 4; ++g)
            bv[g] = *(const f32x4*)(lb + g * 8 + 4 * hi + 32 * kt);
#pragma unroll
          for (int r = 0; r < 16; ++r) {
            float s = ((kt == 0) ? sacc0[r] : sacc1[r]) + bv[r >> 2][r & 3];
            if (needMask) {
              const int rm = (r & 3) + 8 * (r >> 2) + 32 * kt;
              s = (rm > thrh) ? NEG : s;
            }
            pe[r] = __builtin_amdgcn_exp2f(s);
          }
        }
        u32 a0 = cvt_pk_bf16(pe[0], pe[1]), a1 = cvt_pk_bf16(pe[2], pe[3]);
        u32 b0 = cvt_pk_bf16(pe[4], pe[5]), b1 = cvt_pk_bf16(pe[6], pe[7]);
        swap32(a0, b0);
        swap32(a1, b1);
        u32x4 w0 = {a0, a1, b0, b1};
        pa[kt][0] = __builtin_bit_cast(bf16x8, w0);
        u32 c0 = cvt_pk_bf16(pe[8], pe[9]), c1 = cvt_pk_bf16(pe[10], pe[11]);
        u32 d0 = cvt_pk_bf16(pe[12], pe[13]), d1 = cvt_pk_bf16(pe[14], pe[15]);
        swap32(c0, d0);
        swap32(c1, d1);
        u32x4 w1 = {c0, c1, d0, d1};
        pa[kt][1] = __builtin_bit_cast(bf16x8, w1);
      }

      // ---- PV + row-sum: O[q][d] and l[q], q reg-mapped ----
      __builtin_amdgcn_s_setprio(1);
#pragma unroll
      for (int kt = 0; kt < 2; ++kt)
#pragma unroll
        for (int ks = 0; ks < 2; ++ks) {
          const int kq = kt * 2 + ks;
          lacc = MFMA32(pa[kt][ks], ones, lacc);
          const int gsw = ((2 * kq + hi) ^ l7) * 8;
          bf16x8 vf0 = *(const bf16x8*)(lvt + l31 * 64 + gsw);
          bf16x8 vf1 = *(const bf16x8*)(lvt + (l31 + 32) * 64 + gsw);
          o_acc0 = MFMA32(pa[kt][ks], vf0, o_acc0);
          o_acc1 = MFMA32(pa[kt][ks], vf1, o_acc1);
        }
      __builtin_amdgcn_s_setprio(0);
    }

    __syncthreads();  // drains vmcnt(0) (prefetch landed) + all reads of cur done
    cur ^= 1;
  }

  // epilogue: normalize, write [B][S][H*64]
#pragma unroll
  for (int r = 0; r < 16; ++r) {
    const int q = qb + (r & 3) + 8 * (r >> 2) + 4 * hi;
    const float l = lacc[r];
    const float rl = (l > 0.f) ? (1.0f / l) : 0.f;
    O[(size_t)(b * S + q) * 1024 + h * 64 + l31] = f2bf(o_acc0[r] * rl);
    O[(size_t)(b * S + q) * 1024 + h * 64 + 32 + l31] = f2bf(o_acc1[r] * rl);
  }
}

// ---------- kernel 3: output projection (writes fp32 to d_out) ----------
// 128x128 tiles, 256 thr: grid (8, 64) = 512 blocks at 3 blocks/CU.

__global__ __launch_bounds__(256, 3) void oproj_kernel(
    const u16* __restrict__ A, const u16* __restrict__ w_o, float* __restrict__ out) {
  __shared__ u16 lds[24576];  // 48 KB triple-buf
  f32x4 acc[4][4];
  const int row0 = blockIdx.y * 128;
  const int col0 = blockIdx.x * 128;
  gemm_tb128(A, w_o, row0, col0, lds, acc);
  const int tid = threadIdx.x;
  const int wave = tid >> 6, lane = tid & 63;
  const int fr = lane & 15, quad = lane >> 4;
  const int wm = (wave >> 1) * 64, wn = (wave & 1) * 64;
#pragma unroll
  for (int mt = 0; mt < 4; ++mt)
#pragma unroll
    for (int nt = 0; nt < 4; ++nt) {
      const int ncol = col0 + wn + nt * 16 + fr;
#pragma unroll
      for (int r = 0; r < 4; ++r) {
        const int mrow = row0 + wm + mt * 16 + quad * 4 + r;
        out[(size_t)mrow * 1024 + ncol] = acc[mt][nt][r];
      }
    }
}

// ---------- launch ----------

extern "C" void kernel_launch(void* const* d_in, const int* in_sizes, int n_in,
                              void* d_out, int out_size, void* d_ws, size_t ws_size,
                              hipStream_t stream) {
  const float* x_f = (const float*)d_in[0];     // [4][2048][1024] fp32
  const int* pad = (const int*)d_in[1];         // [4][2048] int32
  const float* wqkv_f = (const float*)d_in[2];  // [3072][1024] fp32
  const float* wo_f = (const float*)d_in[3];    // [1024][1024] fp32
  float* out = (float*)d_out;                   // [4][2048][1024] fp32

  const int NX = 4 * 2048 * 1024;
  const int NWQKV = 3072 * 1024;
  const int NWO = 1024 * 1024;
  const size_t HSZ = (size_t)4 * 16 * 2048 * 64;  // 8M elems per head-tensor

  u16* xb = (u16*)d_ws;            // 16 MB
  u16* wqkvb = xb + NX;            // 6 MB
  u16* wob = wqkvb + NWQKV;        // 2 MB
  u16* q_ws = wob + NWO;           // 16 MB  [B][H][S][64] (pre-scaled, roped)
  u16* k_ws = q_ws + HSZ;          // 16 MB  [B][H][S][64] (roped)
  u16* vt_ws = k_ws + HSZ;         // 16 MB  [B][H][64][S] (transposed)
  u16* attn_ws = vt_ws + HSZ;      // 16 MB  [B*S][D]
  float2* rope_t = (float2*)(attn_ws + HSZ);  // 512 KB [2048][32]

  prep_kernel<<<dim3(12544), dim3(256), 0, stream>>>(x_f, wqkv_f, wo_f, xb, wqkvb,
                                                     wob, rope_t);
  qkv_rope_kernel<<<dim3(24, 32), dim3(512), 0, stream>>>(xb, wqkvb, rope_t, q_ws,
                                                          k_ws, vt_ws);
  flash_attn_kernel<<<dim3(1024), dim3(256), 0, stream>>>(q_ws, k_ws, vt_ws, pad,
                                                          attn_ws);
  oproj_kernel<<<dim3(8, 64), dim3(256), 0, stream>>>(attn_ws, wob, out);
}

// Round 13
// 242.795 us; speedup vs baseline: 1.0636x; 1.0636x over previous
//
#include <hip/hip_runtime.h>

typedef unsigned short u16;
typedef unsigned int u32;
typedef __bf16 bf16x8 __attribute__((ext_vector_type(8)));
typedef float f32x4 __attribute__((ext_vector_type(4)));
typedef float f32x16 __attribute__((ext_vector_type(16)));
typedef u32 u32x4 __attribute__((ext_vector_type(4)));

#define MFMA_BF16(a, b, c) __builtin_amdgcn_mfma_f32_16x16x32_bf16((a), (b), (c), 0, 0, 0)
#define MFMA32(a, b, c) __builtin_amdgcn_mfma_f32_32x32x16_bf16((a), (b), (c), 0, 0, 0)

// log2-domain constant: 0.125 * log2(e), folded into w_qkv Q-rows at prep
#define QSCALE 0.18033688011112042f

#define BARRIER __builtin_amdgcn_s_barrier()
#define LGKM0                                                \
  do {                                                       \
    asm volatile("s_waitcnt lgkmcnt(0)" ::: "memory");       \
    __builtin_amdgcn_sched_barrier(0);                       \
  } while (0)
#define WAIT_VM(N) asm volatile("s_waitcnt vmcnt(" #N ")" ::: "memory")

// ---------- helpers ----------

__device__ __forceinline__ u16 f2bf(float f) {
  u32 u = __builtin_bit_cast(u32, f);
  u += 0x7fffu + ((u >> 16) & 1u);   // RNE
  return (u16)(u >> 16);
}

__device__ __forceinline__ void async_copy16(const void* g, void* l) {
  __builtin_amdgcn_global_load_lds(
      (__attribute__((address_space(1))) void*)g,
      (__attribute__((address_space(3))) void*)l, 16, 0, 0);
}

__device__ __forceinline__ u32 cvt_pk_bf16(float lo, float hi) {
  u32 d;
  asm("v_cvt_pk_bf16_f32 %0, %1, %2" : "=v"(d) : "v"(lo), "v"(hi));
  return d;
}

__device__ __forceinline__ void swap32(u32& a, u32& b) {
  asm("v_permlane32_swap_b32 %0, %1" : "+v"(a), "+v"(b));
}

// ---------- kernel 0: fused fp32->bf16 converts + RoPE cos/sin table ----------

__global__ __launch_bounds__(256) void prep_kernel(
    const float* __restrict__ x_f, const float* __restrict__ wqkv_f,
    const float* __restrict__ wo_f, u16* __restrict__ xb,
    u16* __restrict__ wqkvb, u16* __restrict__ wob, float2* __restrict__ rope_t) {
  const int blk = blockIdx.x;
  if (blk < 12288) {
    const float* src;
    u16* dst;
    int base;
    float scale = 1.0f;
    if (blk < 8192)      { src = x_f;    dst = xb;    base = blk; }
    else if (blk < 11264){ src = wqkv_f; dst = wqkvb; base = blk - 8192;
                           if (base < 1024) scale = QSCALE; }  // Q rows
    else                 { src = wo_f;   dst = wob;   base = blk - 11264; }
    const int i = base * 1024 + threadIdx.x * 4;
    const float4 v = *(const float4*)(src + i);
    ushort4 o;
    o.x = f2bf(v.x * scale); o.y = f2bf(v.y * scale);
    o.z = f2bf(v.z * scale); o.w = f2bf(v.w * scale);
    *(ushort4*)(dst + i) = o;
  } else {
    const int idx = (blk - 12288) * 256 + threadIdx.x;  // [0, 65536)
    const int s = idx >> 5, i = idx & 31;
    const float invf = __builtin_amdgcn_exp2f(-(float)i * 0.41524101186092027f);
    float rev = (float)s * invf * 0.15915494309189535f;  // radians -> revolutions
    rev -= floorf(rev);
    rope_t[idx] = make_float2(__builtin_amdgcn_cosf(rev), __builtin_amdgcn_sinf(rev));
  }
}

// ---------- 256x128 GEMM-BT core, BK=32 TRIPLE-buffer, 1 barrier/K-step ------
// (r8 structure, verified). 512 thr = 8 waves (4M x 2N); per-wave 64x64;
// 72 KB LDS -> 2 blocks/CU. stage(t+2) targets buf (t+2)%3, disjoint from
// read buf -> 1 barrier/K-step; counted WAIT_VM(3). BK=32 rows are 64B ->
// naturally conflict-free reads.

__device__ __forceinline__ void gemm_tb(const u16* __restrict__ A,
                                        const u16* __restrict__ B,
                                        int row0, int col0, u16* lds,
                                        f32x4 acc[4][4]) {
  const int tid = threadIdx.x;
  const int wave = tid >> 6, lane = tid & 63;
  const int fr = lane & 15, quad = lane >> 4;
  const int wm = (wave >> 1) * 64;   // 0,64,128,192
  const int wn = (wave & 1) * 64;    // 0,64

  f32x4 zero = {0.f, 0.f, 0.f, 0.f};
#pragma unroll
  for (int mt = 0; mt < 4; ++mt)
#pragma unroll
    for (int nt = 0; nt < 4; ++nt) acc[mt][nt] = zero;

  // stage K-step t into buf t%3: A 2 insts + B 1 inst per thread
  auto stage = [&](int t) {
    u16* base = lds + (t % 3) * 12288;
    const int k0 = t * 32;
#pragma unroll
    for (int it = 0; it < 2; ++it) {
      const int slot = it * 512 + tid;   // 0..1023
      const int row = slot >> 2, g = slot & 3;
      async_copy16(A + (size_t)(row0 + row) * 1024 + k0 + g * 8, base + slot * 8);
    }
    const int row = tid >> 2, g = tid & 3;
    async_copy16(B + (size_t)(col0 + row) * 1024 + k0 + g * 8,
                 base + 8192 + tid * 8);
  };

  const int aoff = fr * 32 + quad * 8;   // within-A row/frag offset
  stage(0);
  stage(1);
  WAIT_VM(3);   // step 0's 3 loads landed
  BARRIER;

  for (int t = 0; t < 32; ++t) {
    const u16* bs = lds + (t % 3) * 12288;

    bf16x8 a[4], b[4];
#pragma unroll
    for (int m = 0; m < 4; ++m)
      a[m] = *(const bf16x8*)(bs + (wm + m * 16) * 32 + aoff);
#pragma unroll
    for (int n = 0; n < 4; ++n)
      b[n] = *(const bf16x8*)(bs + 8192 + (wn + n * 16) * 32 + aoff);

    if (t + 2 < 32) stage(t + 2);   // disjoint buf: no WAR with current reads

    LGKM0;
    __builtin_amdgcn_s_setprio(1);
#pragma unroll
    for (int m = 0; m < 4; ++m)
#pragma unroll
      for (int n = 0; n < 4; ++n)
        acc[m][n] = MFMA_BF16(a[m], b[n], acc[m][n]);
    __builtin_amdgcn_s_setprio(0);

    if (t + 2 < 32) { WAIT_VM(3); } else { WAIT_VM(0); }  // t+1 resident
    BARRIER;
  }
}

// ---------- 128x128 GEMM-BT core, same schedule, 256 thr (for oproj) ---------
// 4 waves (2M x 2N); per-wave 64x64 = acc[4][4] (identical per-wave work).
// LDS 3 x (A 8KB + B 8KB) = 48 KB -> 3 blocks/CU (12 waves).

__device__ __forceinline__ void gemm_tb128(const u16* __restrict__ A,
                                           const u16* __restrict__ B,
                                           int row0, int col0, u16* lds,
                                           f32x4 acc[4][4]) {
  const int tid = threadIdx.x;           // 0..255
  const int wave = tid >> 6, lane = tid & 63;
  const int fr = lane & 15, quad = lane >> 4;
  const int wm = (wave >> 1) * 64;       // 0,64
  const int wn = (wave & 1) * 64;        // 0,64

  f32x4 zero = {0.f, 0.f, 0.f, 0.f};
#pragma unroll
  for (int mt = 0; mt < 4; ++mt)
#pragma unroll
    for (int nt = 0; nt < 4; ++nt) acc[mt][nt] = zero;

  // stage K-step t into buf t%3: 2 A insts + 2 B insts per thread (4 total)
  auto stage = [&](int t) {
    u16* base = lds + (t % 3) * 8192;
    const int k0 = t * 32;
#pragma unroll
    for (int it = 0; it < 2; ++it) {
      const int slot = it * 256 + tid;   // 0..511
      const int row = slot >> 2, g = slot & 3;
      async_copy16(A + (size_t)(row0 + row) * 1024 + k0 + g * 8, base + slot * 8);
      async_copy16(B + (size_t)(col0 + row) * 1024 + k0 + g * 8,
                   base + 4096 + slot * 8);
    }
  };

  const int aoff = fr * 32 + quad * 8;
  stage(0);
  stage(1);
  WAIT_VM(4);   // step 0's 4 loads landed
  BARRIER;

  for (int t = 0; t < 32; ++t) {
    const u16* bs = lds + (t % 3) * 8192;

    bf16x8 a[4], b[4];
#pragma unroll
    for (int m = 0; m < 4; ++m)
      a[m] = *(const bf16x8*)(bs + (wm + m * 16) * 32 + aoff);
#pragma unroll
    for (int n = 0; n < 4; ++n)
      b[n] = *(const bf16x8*)(bs + 4096 + (wn + n * 16) * 32 + aoff);

    if (t + 2 < 32) stage(t + 2);

    LGKM0;
    __builtin_amdgcn_s_setprio(1);
#pragma unroll
    for (int m = 0; m < 4; ++m)
#pragma unroll
      for (int n = 0; n < 4; ++n)
        acc[m][n] = MFMA_BF16(a[m], b[n], acc[m][n]);
    __builtin_amdgcn_s_setprio(0);

    if (t + 2 < 32) { WAIT_VM(4); } else { WAIT_VM(0); }
    BARRIER;
  }
}

// ---------- kernel 1: QKV projection + RoPE (r8 structure, unchanged) --------
// 256x128 tiles: grid (24, 32) = 768 blocks at 2 blocks/CU; XCD-chunked remap.

__global__ __launch_bounds__(512, 4) void qkv_rope_kernel(
    const u16* __restrict__ x, const u16* __restrict__ w_qkv,
    const float2* __restrict__ rope_t,
    u16* __restrict__ q_ws, u16* __restrict__ k_ws, u16* __restrict__ vt_ws) {
  __shared__ u16 lds[36864];  // 72 KB: gemm triple-buf; epilogue reuses it
  f32x4 acc[4][4];
  const int lin0 = blockIdx.x + 24 * blockIdx.y;   // 0..767
  const int lin = (lin0 & 7) * 96 + (lin0 >> 3);   // bijective XCD-chunk remap
  const int row0 = (lin / 24) * 256;  // M = 8192
  const int col0 = (lin % 24) * 128;  // N = 3072
  gemm_tb(x, w_qkv, row0, col0, lds, acc);

  const int tid = threadIdx.x;
  const int wave = tid >> 6, lane = tid & 63;
  const int fr = lane & 15, quad = lane >> 4;
  const int wm = (wave >> 1) * 64, wn = (wave & 1) * 64;
  const int region = col0 >> 10;      // 0=Q 1=K 2=V (block-uniform; 1024%128==0)
  const int f0 = col0 & 1023;
  const int s0r = row0 & 2047;
  const int bb = row0 >> 11;
  const int h0 = f0 >> 6;             // block covers heads h0, h0+1

  if (region < 2) {
    // rotate in registers, stage [m 256][n 128] (stride 136)
#pragma unroll
    for (int mt = 0; mt < 4; ++mt) {
#pragma unroll
      for (int nt = 0; nt < 4; ++nt) {
        const int n = wn + nt * 16 + fr;
        const int d = n & 63;  // col0/wn are 64-aligned
#pragma unroll
        for (int r = 0; r < 4; ++r) {
          const int m = wm + mt * 16 + quad * 4 + r;
          const float own = acc[mt][nt][r];
          const float part = __shfl_xor(own, 1);
          const int s = s0r + m;
          const float2 cssn = rope_t[s * 32 + (d >> 1)];
          const float val = (d & 1) ? (part * cssn.y + own * cssn.x)
                                    : (own * cssn.x - part * cssn.y);
          lds[m * 136 + n] = f2bf(val);
        }
      }
    }
    __syncthreads();
    u16* dst = (region == 0) ? q_ws : k_ws;
#pragma unroll
    for (int j = 0; j < 8; ++j) {
      const int idx2 = j * 512 + tid;       // 0..4095
      const int m = idx2 >> 4;              // 0..255
      const int rem = idx2 & 15;
      const int hf = rem >> 3;              // head half (0/1)
      const int c8 = (rem & 7) * 8;
      const uint4 v = *(const uint4*)(lds + m * 136 + hf * 64 + c8);
      *(uint4*)(dst + ((size_t)(bb * 16 + h0 + hf) * 2048 + s0r + m) * 64 + c8) = v;
    }
  } else {
    // stage transposed [n 128][m 256] (stride 264)
#pragma unroll
    for (int mt = 0; mt < 4; ++mt)
#pragma unroll
      for (int nt = 0; nt < 4; ++nt) {
        const int n = wn + nt * 16 + fr;
#pragma unroll
        for (int r = 0; r < 4; ++r) {
          const int m = wm + mt * 16 + quad * 4 + r;
          lds[n * 264 + m] = f2bf(acc[mt][nt][r]);
        }
      }
    __syncthreads();
#pragma unroll
    for (int j = 0; j < 8; ++j) {
      const int idx2 = j * 512 + tid;       // 0..4095
      const int n = idx2 >> 5;              // 0..127
      const int mc = (idx2 & 31) * 8;       // 0..248
      const int h = h0 + (n >> 6);
      const int d = n & 63;
      const uint4 v = *(const uint4*)(lds + n * 264 + mc);
      *(uint4*)(vt_ws + ((size_t)(bb * 16 + h) * 64 + d) * 2048 + s0r + mc) = v;
    }
  }
}

// ---------- kernel 2: causal flash attention, swapped-QK 32x32 in-reg softmax -
// r3 structure at __launch_bounds__(256,3) -- the verified 69 µs config.
// (r12 measured (256,4): VGPR squeezed 72->64, ~19MB scratch spill traffic,
// 86 µs. Kernel needs its 72 registers; occupancy push via bounds = spill.)

__global__ __launch_bounds__(256, 3) void flash_attn_kernel(
    const u16* __restrict__ Q, const u16* __restrict__ K, const u16* __restrict__ Vt,
    const int* __restrict__ pad, u16* __restrict__ O) {
  const int S = 2048;
  const int idx = blockIdx.x;
  const int bh = idx & 63;
  const int b = bh >> 4, h = bh & 15;
  // balanced q-tile remap: perm = [[0,1,2,3],[7,6,5,4],[8,9,10,11],[15,14,13,12]]
  const int j = (idx >> 6) & 3;
  const int sr = idx >> 8;
  const int qt_rev = (sr >> 1) * 8 + ((sr & 1) ? (7 - j) : j);
  const int q0 = (15 - qt_rev) * 128;
  const u16* Qh = Q + (size_t)bh * S * 64;
  const u16* Kh = K + (size_t)bh * S * 64;
  const u16* Vth = Vt + (size_t)bh * 64 * S;
  const int tid = threadIdx.x, wave = tid >> 6, lane = tid & 63;
  const int l31 = lane & 31, hi = lane >> 5, l7 = lane & 7;

  __shared__ u16 lds_k[2][64 * 64];    // dbuf [kpos 64][d 64] swizzled  16 KB
  __shared__ u16 lds_vt[2][64 * 64];   // dbuf [d 64][kpos 64] swizzled  16 KB
  __shared__ float lds_biasf[2][64];   // {0, -inf} per kpos             512 B

  const int qb = q0 + wave * 32;  // wave's first q row

  // Q as B-operand: lane holds Q[qb + l31][d = c*16 + hi*8 + 0..7]
  bf16x8 qfrag[4];
#pragma unroll
  for (int c = 0; c < 4; ++c)
    qfrag[c] = *(const bf16x8*)(Qh + (size_t)(qb + l31) * 64 + c * 16 + hi * 8);

  bf16x8 ones;
#pragma unroll
  for (int jj = 0; jj < 8; ++jj) ones[jj] = (__bf16)1.0f;

  f32x16 o_acc0, o_acc1, lacc;
#pragma unroll
  for (int r = 0; r < 16; ++r) { o_acc0[r] = 0.f; o_acc1[r] = 0.f; lacc[r] = 0.f; }

  const float NEG = -__builtin_inff();
  int pv0 = 1, pv1 = 1;

  auto stage = [&](int k0, int bufi) {
#pragma unroll
    for (int it = 0; it < 2; ++it) {
      const int slot = it * 256 + tid;   // 0..511
      const int row = slot >> 3;         // 0..63
      const int g = slot & 7;
      const int gs = (g ^ (row & 7)) * 8;  // inverse-swizzled source granule
      async_copy16(Kh + (size_t)(k0 + row) * 64 + gs, &lds_k[bufi][slot * 8]);
      async_copy16(Vth + (size_t)row * 2048 + k0 + gs, &lds_vt[bufi][slot * 8]);
    }
    if (tid < 64) lds_biasf[bufi][tid] = pad[b * S + k0 + tid] ? 0.f : NEG;
    const int pvn = pad[b * S + k0 + lane];   // per-wave ballot source
    if (bufi) pv1 = pvn; else pv0 = pvn;
  };

  const int kend = q0 + 64;  // last k-tile origin (inclusive)
  stage(0, 0);
  __syncthreads();  // drains vmcnt(0): tile 0 resident
  int cur = 0;

  for (int k0 = 0; k0 <= kend; k0 += 64) {
    if (k0 < kend) stage(k0 + 64, cur ^ 1);  // prefetch next tile

    if (k0 <= qb + 31) {  // wave-uniform: skip fully-masked tiles
      const u16* lk = lds_k[cur];
      const u16* lvt = lds_vt[cur];
      const float* lb = lds_biasf[cur];
      const int pvc = cur ? pv1 : pv0;
      const bool fast = (__ballot(pvc != 0) == ~0ull);
      const bool needMask = (k0 + 63 > qb);
      const int thrh = qb + l31 - k0 - 4 * hi;  // mask iff rm+32*kt > thrh

      // ---- QK^T swapped: S[kpos][q], kpos reg-mapped, q = l31 ----
      f32x16 sacc0, sacc1;
#pragma unroll
      for (int r = 0; r < 16; ++r) { sacc0[r] = 0.f; sacc1[r] = 0.f; }
#pragma unroll
      for (int c = 0; c < 4; ++c) {
        const int gsw = ((2 * c + hi) ^ l7) * 8;
        bf16x8 kf0 = *(const bf16x8*)(lk + l31 * 64 + gsw);
        bf16x8 kf1 = *(const bf16x8*)(lk + (l31 + 32) * 64 + gsw);
        sacc0 = MFMA32(kf0, qfrag[c], sacc0);
        sacc1 = MFMA32(kf1, qfrag[c], sacc1);
      }

      // ---- softmax in-register + pack to PV A-frags ----
      bf16x8 pa[2][2];
#pragma unroll
      for (int kt = 0; kt < 2; ++kt) {
        float pe[16];
        if (fast) {
#pragma unroll
          for (int r = 0; r < 16; ++r) {
            float s = (kt == 0) ? sacc0[r] : sacc1[r];
            if (needMask) {
              const int rm = (r & 3) + 8 * (r >> 2) + 32 * kt;
              s = (rm > thrh) ? NEG : s;
            }
            pe[r] = __builtin_amdgcn_exp2f(s);
          }
        } else {
          f32x4 bv[4];
#pragma unroll
          for (int g = 0; g < 4; ++g)
            bv[g] = *(const f32x4*)(lb + g * 8 + 4 * hi + 32 * kt);
#pragma unroll
          for (int r = 0; r < 16; ++r) {
            float s = ((kt == 0) ? sacc0[r] : sacc1[r]) + bv[r >> 2][r & 3];
            if (needMask) {
              const int rm = (r & 3) + 8 * (r >> 2) + 32 * kt;
              s = (rm > thrh) ? NEG : s;
            }
            pe[r] = __builtin_amdgcn_exp2f(s);
          }
        }
        u32 a0 = cvt_pk_bf16(pe[0], pe[1]), a1 = cvt_pk_bf16(pe[2], pe[3]);
        u32 b0 = cvt_pk_bf16(pe[4], pe[5]), b1 = cvt_pk_bf16(pe[6], pe[7]);
        swap32(a0, b0);
        swap32(a1, b1);
        u32x4 w0 = {a0, a1, b0, b1};
        pa[kt][0] = __builtin_bit_cast(bf16x8, w0);
        u32 c0 = cvt_pk_bf16(pe[8], pe[9]), c1 = cvt_pk_bf16(pe[10], pe[11]);
        u32 d0 = cvt_pk_bf16(pe[12], pe[13]), d1 = cvt_pk_bf16(pe[14], pe[15]);
        swap32(c0, d0);
        swap32(c1, d1);
        u32x4 w1 = {c0, c1, d0, d1};
        pa[kt][1] = __builtin_bit_cast(bf16x8, w1);
      }

      // ---- PV + row-sum: O[q][d] and l[q], q reg-mapped ----
      __builtin_amdgcn_s_setprio(1);
#pragma unroll
      for (int kt = 0; kt < 2; ++kt)
#pragma unroll
        for (int ks = 0; ks < 2; ++ks) {
          const int kq = kt * 2 + ks;
          lacc = MFMA32(pa[kt][ks], ones, lacc);
          const int gsw = ((2 * kq + hi) ^ l7) * 8;
          bf16x8 vf0 = *(const bf16x8*)(lvt + l31 * 64 + gsw);
          bf16x8 vf1 = *(const bf16x8*)(lvt + (l31 + 32) * 64 + gsw);
          o_acc0 = MFMA32(pa[kt][ks], vf0, o_acc0);
          o_acc1 = MFMA32(pa[kt][ks], vf1, o_acc1);
        }
      __builtin_amdgcn_s_setprio(0);
    }

    __syncthreads();  // drains vmcnt(0) (prefetch landed) + all reads of cur done
    cur ^= 1;
  }

  // epilogue: normalize, write [B][S][H*64]
#pragma unroll
  for (int r = 0; r < 16; ++r) {
    const int q = qb + (r & 3) + 8 * (r >> 2) + 4 * hi;
    const float l = lacc[r];
    const float rl = (l > 0.f) ? (1.0f / l) : 0.f;
    O[(size_t)(b * S + q) * 1024 + h * 64 + l31] = f2bf(o_acc0[r] * rl);
    O[(size_t)(b * S + q) * 1024 + h * 64 + 32 + l31] = f2bf(o_acc1[r] * rl);
  }
}

// ---------- kernel 3: output projection (writes fp32 to d_out) ----------
// 128x128 tiles, 256 thr: grid (8, 64) = 512 blocks at 3 blocks/CU.

__global__ __launch_bounds__(256, 3) void oproj_kernel(
    const u16* __restrict__ A, const u16* __restrict__ w_o, float* __restrict__ out) {
  __shared__ u16 lds[24576];  // 48 KB triple-buf
  f32x4 acc[4][4];
  const int row0 = blockIdx.y * 128;
  const int col0 = blockIdx.x * 128;
  gemm_tb128(A, w_o, row0, col0, lds, acc);
  const int tid = threadIdx.x;
  const int wave = tid >> 6, lane = tid & 63;
  const int fr = lane & 15, quad = lane >> 4;
  const int wm = (wave >> 1) * 64, wn = (wave & 1) * 64;
#pragma unroll
  for (int mt = 0; mt < 4; ++mt)
#pragma unroll
    for (int nt = 0; nt < 4; ++nt) {
      const int ncol = col0 + wn + nt * 16 + fr;
#pragma unroll
      for (int r = 0; r < 4; ++r) {
        const int mrow = row0 + wm + mt * 16 + quad * 4 + r;
        out[(size_t)mrow * 1024 + ncol] = acc[mt][nt][r];
      }
    }
}

// ---------- launch ----------

extern "C" void kernel_launch(void* const* d_in, const int* in_sizes, int n_in,
                              void* d_out, int out_size, void* d_ws, size_t ws_size,
                              hipStream_t stream) {
  const float* x_f = (const float*)d_in[0];     // [4][2048][1024] fp32
  const int* pad = (const int*)d_in[1];         // [4][2048] int32
  const float* wqkv_f = (const float*)d_in[2];  // [3072][1024] fp32
  const float* wo_f = (const float*)d_in[3];    // [1024][1024] fp32
  float* out = (float*)d_out;                   // [4][2048][1024] fp32

  const int NX = 4 * 2048 * 1024;
  const int NWQKV = 3072 * 1024;
  const int NWO = 1024 * 1024;
  const size_t HSZ = (size_t)4 * 16 * 2048 * 64;  // 8M elems per head-tensor

  u16* xb = (u16*)d_ws;            // 16 MB
  u16* wqkvb = xb + NX;            // 6 MB
  u16* wob = wqkvb + NWQKV;        // 2 MB
  u16* q_ws = wob + NWO;           // 16 MB  [B][H][S][64] (pre-scaled, roped)
  u16* k_ws = q_ws + HSZ;          // 16 MB  [B][H][S][64] (roped)
  u16* vt_ws = k_ws + HSZ;         // 16 MB  [B][H][64][S] (transposed)
  u16* attn_ws = vt_ws + HSZ;      // 16 MB  [B*S][D]
  float2* rope_t = (float2*)(attn_ws + HSZ);  // 512 KB [2048][32]

  prep_kernel<<<dim3(12544), dim3(256), 0, stream>>>(x_f, wqkv_f, wo_f, xb, wqkvb,
                                                     wob, rope_t);
  qkv_rope_kernel<<<dim3(24, 32), dim3(512), 0, stream>>>(xb, wqkvb, rope_t, q_ws,
                                                          k_ws, vt_ws);
  flash_attn_kernel<<<dim3(1024), dim3(256), 0, stream>>>(q_ws, k_ws, vt_ws, pad,
                                                          attn_ws);
  oproj_kernel<<<dim3(8, 64), dim3(256), 0, stream>>>(attn_ws, wob, out);
}